// Round 17
// baseline (1739.135 us; speedup 1.0000x reference)
//
#include <hip/hip_runtime.h>

typedef __bf16 bf16_t;
typedef __bf16 bf16x8 __attribute__((ext_vector_type(8)));
typedef __bf16 bf16x4 __attribute__((ext_vector_type(4)));
typedef float  f32x4  __attribute__((ext_vector_type(4)));

#define QKV_STR 3072   // fused QKV row stride (elements)

__device__ __forceinline__ void gload16(const bf16_t* g, bf16_t* l) {
    __builtin_amdgcn_global_load_lds(
        (const __attribute__((address_space(1))) void*)(g),
        (__attribute__((address_space(3))) void*)(l), 16, 0, 0);
}

// ---------------- f32 -> bf16 cast ----------------
__global__ __launch_bounds__(256) void cast_bf16_kernel(const float* __restrict__ in,
                                                        bf16_t* __restrict__ out, int n4) {
    int i = blockIdx.x * 256 + threadIdx.x;
    if (i >= n4) return;
    f32x4 v = *reinterpret_cast<const f32x4*>(in + (size_t)i * 4);
    bf16x4 o;
    o[0] = (bf16_t)v[0]; o[1] = (bf16_t)v[1]; o[2] = (bf16_t)v[2]; o[3] = (bf16_t)v[3];
    *reinterpret_cast<bf16x4*>(out + (size_t)i * 4) = o;
}

// four 1M-element weight casts in one dispatch (grid 4096)
__global__ __launch_bounds__(256) void cast4_kernel(const float* __restrict__ w0,
                                                    const float* __restrict__ w1,
                                                    const float* __restrict__ w2,
                                                    const float* __restrict__ w3,
                                                    bf16_t* __restrict__ o0,
                                                    bf16_t* __restrict__ o1,
                                                    bf16_t* __restrict__ o2,
                                                    bf16_t* __restrict__ o3) {
    int which = blockIdx.x >> 10;
    int i = (blockIdx.x & 1023) * 256 + threadIdx.x;
    const float* in = (which == 0) ? w0 : (which == 1) ? w1 : (which == 2) ? w2 : w3;
    bf16_t*     out = (which == 0) ? o0 : (which == 1) ? o1 : (which == 2) ? o2 : o3;
    f32x4 v = *reinterpret_cast<const f32x4*>(in + (size_t)i * 4);
    bf16x4 o;
    o[0] = (bf16_t)v[0]; o[1] = (bf16_t)v[1]; o[2] = (bf16_t)v[2]; o[3] = (bf16_t)v[3];
    *reinterpret_cast<bf16x4*>(out + (size_t)i * 4) = o;
}

__device__ __forceinline__ bf16x8 sigma8(bf16x8 x) {
    bf16x8 o;
#pragma unroll
    for (int j = 0; j < 8; j++) {
        float f = (float)x[j];
        float sg = f > 0.f ? f + 1.f : __expf(f);
        o[j] = (bf16_t)sg;
    }
    return o;
}

// ---------------- 256x256 GEMM, BK=32, 2-slot LDS ring (64KB -> 2 blocks/CU) ----------------
// Per iter: vmcnt(4) [tile t landed] -> barrier -> ds_read frags -> lgkmcnt(0) -> barrier
// [slot reusable] -> STAGE(t+2) -> MFMA. Two co-resident blocks overlap each other's stalls.
template <int OUT_BF16>
__global__ __launch_bounds__(512, 4) void gemm256(const bf16_t* __restrict__ A,
                                                  const bf16_t* __restrict__ Bm,
                                                  void* __restrict__ Cv,
                                                  int M, int N, int K) {
    __shared__ bf16_t As[2][256 * 32];
    __shared__ bf16_t Bs[2][256 * 32];

    int nbn = N >> 8;
    int nwg = (M >> 8) * nbn;
    int bid = blockIdx.x;
    int wg = ((nwg & 7) == 0) ? ((bid & 7) * (nwg >> 3) + (bid >> 3)) : bid;
    int bm = wg / nbn, bn = wg % nbn;

    int tid = threadIdx.x;
    int w = tid >> 6, lane = tid & 63;
    int wm = w >> 2, wn = w & 3;
    int lr = lane & 15, lk = lane >> 4;

    int srow = lane >> 2;
    int schunk = (lane & 3) ^ ((lane >> 3) & 3);
    const bf16_t* gA0 = A  + (size_t)(bm * 256 + w * 32 + srow) * K + schunk * 8;
    const bf16_t* gA1 = gA0 + (size_t)16 * K;
    const bf16_t* gB0 = Bm + (size_t)(bn * 256 + w * 32 + srow) * K + schunk * 8;
    const bf16_t* gB1 = gB0 + (size_t)16 * K;
    int lO0 = (w * 32) * 32 + lane * 8;
    int lO1 = (w * 32 + 16) * 32 + lane * 8;

    int chunkb = (lk ^ ((lr >> 1) & 3)) << 4;
    int aoff[8], boff[4];
#pragma unroll
    for (int mi = 0; mi < 8; mi++) aoff[mi] = (wm * 128 + mi * 16 + lr) * 64 + chunkb;
#pragma unroll
    for (int ni = 0; ni < 4; ni++) boff[ni] = (wn * 64 + ni * 16 + lr) * 64 + chunkb;

    f32x4 acc[8][4];
#pragma unroll
    for (int mi = 0; mi < 8; mi++)
#pragma unroll
        for (int ni = 0; ni < 4; ni++) acc[mi][ni] = (f32x4){0.f, 0.f, 0.f, 0.f};

    const int NT = K >> 5;

    auto STAGE = [&](int t) {
        int slot = t & 1;
        size_t ko = (size_t)t * 32;
        gload16(gA0 + ko, &As[slot][lO0]);
        gload16(gA1 + ko, &As[slot][lO1]);
        gload16(gB0 + ko, &Bs[slot][lO0]);
        gload16(gB1 + ko, &Bs[slot][lO1]);
    };

    STAGE(0); STAGE(1);

#pragma unroll 1
    for (int t = 0; t < NT; ++t) {
        // wait for tile t's own 4 loads (t+1's stay in flight)
        if (t + 1 < NT) asm volatile("s_waitcnt vmcnt(4)" ::: "memory");
        else            asm volatile("s_waitcnt vmcnt(0)" ::: "memory");
        __builtin_amdgcn_sched_barrier(0);
        __builtin_amdgcn_s_barrier();          // all waves: tile t landed
        __builtin_amdgcn_sched_barrier(0);

        const char* pa = (const char*)(&As[t & 1][0]);
        const char* pb = (const char*)(&Bs[t & 1][0]);
        bf16x8 af[8], bfr[4];
#pragma unroll
        for (int ni = 0; ni < 4; ni++)
            bfr[ni] = *reinterpret_cast<const bf16x8*>(pb + boff[ni]);
#pragma unroll
        for (int mi = 0; mi < 8; mi++)
            af[mi] = *reinterpret_cast<const bf16x8*>(pa + aoff[mi]);

        asm volatile("s_waitcnt lgkmcnt(0)" ::: "memory");
        __builtin_amdgcn_sched_barrier(0);
        __builtin_amdgcn_s_barrier();          // all waves' slot reads done -> reusable
        __builtin_amdgcn_sched_barrier(0);

        if (t + 2 < NT) STAGE(t + 2);

        __builtin_amdgcn_s_setprio(1);
#pragma unroll
        for (int mi = 0; mi < 8; mi++)
#pragma unroll
            for (int ni = 0; ni < 4; ni++)
                acc[mi][ni] = __builtin_amdgcn_mfma_f32_16x16x32_bf16(af[mi], bfr[ni], acc[mi][ni], 0, 0, 0);
        __builtin_amdgcn_s_setprio(0);
    }

    int row0 = bm * 256 + wm * 128 + lk * 4;
    int col0 = bn * 256 + wn * 64 + lr;
#pragma unroll
    for (int mi = 0; mi < 8; mi++)
#pragma unroll
        for (int ni = 0; ni < 4; ni++)
#pragma unroll
            for (int jj = 0; jj < 4; jj++) {
                size_t idx = (size_t)(row0 + mi * 16 + jj) * N + (col0 + ni * 16);
                float v = acc[mi][ni][jj];
                if (OUT_BF16) reinterpret_cast<bf16_t*>(Cv)[idx] = (bf16_t)v;
                else          reinterpret_cast<float*>(Cv)[idx]  = v;
            }
}

// ---------------- parallel local attention on fused QKV (row stride 3072) ----------------
// Emits: sigma(k) DENSE -> skg; sigma(k)^T dense -> skTg; v^T in-place over V cols;
// column sums; A_dot.
__global__ __launch_bounds__(256) void attn_kernel(bf16_t* __restrict__ QKV,
                                                   bf16_t* __restrict__ skTg,
                                                   bf16_t* __restrict__ skg,
                                                   float* __restrict__ csum,
                                                   bf16_t* __restrict__ Adot) {
    __shared__ bf16_t kS[64 * 72];
    __shared__ bf16_t vS[64 * 72];
    __shared__ bf16_t skT[64 * 72];
    __shared__ bf16_t vT[64 * 72];
    __shared__ bf16_t pS[64 * 72];
    __shared__ float  scr[64 * 68];

    int u = blockIdx.x;
    int bh = u >> 6, s = u & 63;
    int b = bh >> 4, h = bh & 15;
    int tid = threadIdx.x;
    int w = tid >> 6, lane = tid & 63;
    int lr = lane & 15, lk = lane >> 4;
    int r = tid >> 2, qd = tid & 3, c0 = qd << 4;

    bf16_t* qp = QKV + (size_t)(b * 4096 + s * 64) * QKV_STR + (size_t)h * 64;
    bf16_t* kp = qp + 1024;
    bf16_t* vp = qp + 2048;
    size_t sb = ((size_t)bh * 64 + s) * 4096;

    {
        bf16x8 k0 = *reinterpret_cast<const bf16x8*>(kp + (size_t)r * QKV_STR + c0);
        bf16x8 k1 = *reinterpret_cast<const bf16x8*>(kp + (size_t)r * QKV_STR + c0 + 8);
        bf16x8 v0 = *reinterpret_cast<const bf16x8*>(vp + (size_t)r * QKV_STR + c0);
        bf16x8 v1 = *reinterpret_cast<const bf16x8*>(vp + (size_t)r * QKV_STR + c0 + 8);
        *reinterpret_cast<bf16x8*>(&kS[r * 72 + c0])     = k0;
        *reinterpret_cast<bf16x8*>(&kS[r * 72 + c0 + 8]) = k1;
        *reinterpret_cast<bf16x8*>(&vS[r * 72 + c0])     = v0;
        *reinterpret_cast<bf16x8*>(&vS[r * 72 + c0 + 8]) = v1;
        bf16x8 s0 = sigma8(k0), s1 = sigma8(k1);
        *reinterpret_cast<bf16x8*>(skg + sb + (size_t)r * 64 + c0)     = s0;
        *reinterpret_cast<bf16x8*>(skg + sb + (size_t)r * 64 + c0 + 8) = s1;
#pragma unroll
        for (int j = 0; j < 8; j++) {
            skT[(c0 + j) * 72 + r]     = s0[j];
            skT[(c0 + 8 + j) * 72 + r] = s1[j];
            vT[(c0 + j) * 72 + r]      = v0[j];
            vT[(c0 + 8 + j) * 72 + r]  = v1[j];
        }
    }
    __syncthreads();

    if (tid < 64) {
        float acc = 0.f;
#pragma unroll 8
        for (int t = 0; t < 64; t++) acc += (float)skT[tid * 72 + t];
        csum[((size_t)bh * 64 + s) * 64 + tid] = acc;
    }
    *reinterpret_cast<bf16x8*>(skTg + sb + (size_t)r * 64 + c0) =
        *reinterpret_cast<const bf16x8*>(&skT[r * 72 + c0]);
    *reinterpret_cast<bf16x8*>(skTg + sb + (size_t)r * 64 + c0 + 8) =
        *reinterpret_cast<const bf16x8*>(&skT[r * 72 + c0 + 8]);
    *reinterpret_cast<bf16x8*>(vp + (size_t)r * QKV_STR + c0) =
        *reinterpret_cast<const bf16x8*>(&vT[r * 72 + c0]);
    *reinterpret_cast<bf16x8*>(vp + (size_t)r * QKV_STR + c0 + 8) =
        *reinterpret_cast<const bf16x8*>(&vT[r * 72 + c0 + 8]);

    {
        bf16x8 aq[2];
#pragma unroll
        for (int ks = 0; ks < 2; ks++)
            aq[ks] = *reinterpret_cast<const bf16x8*>(qp + (size_t)(w * 16 + lr) * QKV_STR + lk * 8 + ks * 32);
        f32x4 sc[4];
#pragma unroll
        for (int ct = 0; ct < 4; ct++) {
            sc[ct] = (f32x4){0.f, 0.f, 0.f, 0.f};
#pragma unroll
            for (int ks = 0; ks < 2; ks++) {
                bf16x8 bfrag = *reinterpret_cast<const bf16x8*>(&kS[(ct * 16 + lr) * 72 + lk * 8 + ks * 32]);
                sc[ct] = __builtin_amdgcn_mfma_f32_16x16x32_bf16(aq[ks], bfrag, sc[ct], 0, 0, 0);
            }
        }
#pragma unroll
        for (int ct = 0; ct < 4; ct++)
#pragma unroll
            for (int j = 0; j < 4; j++)
                scr[(w * 16 + lk * 4 + j) * 68 + ct * 16 + lr] = sc[ct][j] * 0.125f;
    }
    __syncthreads();

    {
        float p[16];
        float mx = -3.4e38f;
        const float* srow_p = &scr[r * 68 + c0];
#pragma unroll
        for (int i = 0; i < 16; i++) {
            int c = c0 + i;
            float v = (c <= r) ? srow_p[i] : -3.4e38f;
            p[i] = v;
            mx = fmaxf(mx, v);
        }
        mx = fmaxf(mx, __shfl_xor(mx, 1));
        mx = fmaxf(mx, __shfl_xor(mx, 2));
        float sum = 0.f;
#pragma unroll
        for (int i = 0; i < 16; i++) {
            int c = c0 + i;
            float e = (c <= r) ? __expf(p[i] - mx) : 0.f;
            p[i] = e;
            sum += e;
        }
        sum += __shfl_xor(sum, 1);
        sum += __shfl_xor(sum, 2);
        float inv = 1.f / sum;
        bf16x8 p0, p1;
#pragma unroll
        for (int j = 0; j < 8; j++) {
            p0[j] = (bf16_t)(p[j] * inv);
            p1[j] = (bf16_t)(p[8 + j] * inv);
        }
        *reinterpret_cast<bf16x8*>(&pS[r * 72 + c0])     = p0;
        *reinterpret_cast<bf16x8*>(&pS[r * 72 + c0 + 8]) = p1;
    }
    __syncthreads();

    {
        f32x4 ad[4];
#pragma unroll
        for (int ct = 0; ct < 4; ct++) {
            ad[ct] = (f32x4){0.f, 0.f, 0.f, 0.f};
#pragma unroll
            for (int ks = 0; ks < 2; ks++) {
                bf16x8 afrag = *reinterpret_cast<const bf16x8*>(&pS[(w * 16 + lr) * 72 + lk * 8 + ks * 32]);
                bf16x8 bfrag = *reinterpret_cast<const bf16x8*>(&vT[(ct * 16 + lr) * 72 + lk * 8 + ks * 32]);
                ad[ct] = __builtin_amdgcn_mfma_f32_16x16x32_bf16(afrag, bfrag, ad[ct], 0, 0, 0);
            }
        }
#pragma unroll
        for (int ct = 0; ct < 4; ct++)
#pragma unroll
            for (int j = 0; j < 4; j++)
                kS[(w * 16 + lk * 4 + j) * 72 + ct * 16 + lr] = (bf16_t)ad[ct][j];
    }
    __syncthreads();
    *reinterpret_cast<bf16x8*>(Adot + sb + (size_t)r * 64 + c0) =
        *reinterpret_cast<const bf16x8*>(&kS[r * 72 + c0]);
    *reinterpret_cast<bf16x8*>(Adot + sb + (size_t)r * 64 + c0 + 8) =
        *reinterpret_cast<const bf16x8*>(&kS[r * 72 + c0 + 8]);
}

// ---------------- z prefix over segments (batched loads, register prefix) ----------------
__global__ __launch_bounds__(64) void zprefix_kernel(const float* __restrict__ csum,
                                                     float* __restrict__ zx,
                                                     float* __restrict__ zfin) {
    int bh = blockIdx.x;
    int d = threadIdx.x;
    float c[64];
#pragma unroll
    for (int s = 0; s < 64; s++)
        c[s] = csum[((size_t)bh * 64 + s) * 64 + d];
    float z = 0.f;
#pragma unroll
    for (int s = 0; s < 64; s++) {
        zx[((size_t)bh * 64 + s) * 64 + d] = z;
        z += c[s];
    }
    zfin[bh * 64 + d] = z;
}

// ---------------- k-side denominators only: 1/(sigma(k) . z + eps) (dense sigma(k)) -------
__global__ __launch_bounds__(64) void denomk_kernel(const bf16_t* __restrict__ skg,
                                                    const float* __restrict__ zx,
                                                    float* __restrict__ invk) {
    __shared__ float zL[64];
    int u = blockIdx.x;
    int tid = threadIdx.x;
    zL[tid] = zx[(size_t)u * 64 + tid];
    __syncthreads();
    const bf16_t* src = skg + (size_t)u * 4096 + (size_t)tid * 64;
    float acc = 0.f;
#pragma unroll
    for (int blk = 0; blk < 8; blk++) {
        bf16x8 v = *reinterpret_cast<const bf16x8*>(src + blk * 8);
#pragma unroll
        for (int j = 0; j < 8; j++)
            acc = __builtin_fmaf((float)v[j], zL[blk * 8 + j], acc);
    }
    invk[(size_t)u * 64 + tid] = 1.f / (acc + 1e-6f);
}

// ---------------- k-side recurrence scan: 1 wave per block, no barriers, depth-1 prefetch ----
// grid 256: bh = blk & 63, cq = blk >> 6 (column quarter). M cols c0..c0+15 per block.
__global__ __launch_bounds__(64, 1) void scan_kernel(const bf16_t* __restrict__ QKV,
                                                     const bf16_t* __restrict__ skg,
                                                     const bf16_t* __restrict__ skTg,
                                                     const float* __restrict__ invk,
                                                     bf16_t* __restrict__ Msnap,
                                                     float* __restrict__ Mfin) {
    __shared__ bf16_t MbL[16 * 72];  // M^T slice (swizzled rows)
    __shared__ bf16_t uTL[16 * 72];  // v^T -> u^T slice (swizzled)
    __shared__ float  ikL[64];

    int blk = blockIdx.x;
    int bh = blk & 63, cq = blk >> 6;
    int c0 = cq << 4;
    int b = bh >> 4, h = bh & 15;
    int lane = threadIdx.x;
    int lr = lane & 15, lk = lane >> 4;
    int vr = lane >> 2, vt0 = (lane & 3) << 4;

    const bf16_t* vTb = QKV + 2048;
    size_t chbase = (size_t)(b * 4096) * QKV_STR + (size_t)h * 64;
    size_t stbase = (size_t)bh * 64 * 4096;
    const size_t SEG = (size_t)64 * QKV_STR;

    auto swz = [](bf16_t* base, int row, int intra) -> bf16_t* {
        return (bf16_t*)((char*)base + row * 144 + (intra ^ ((row & 7) << 4)));
    };

    for (int i = lane; i < 16 * 72; i += 64) MbL[i] = (bf16_t)0.f;
    f32x4 Mreg[4];
#pragma unroll
    for (int rt = 0; rt < 4; rt++) Mreg[rt] = (f32x4){0.f, 0.f, 0.f, 0.f};

    bf16x8 cK[4][2], cT[4][2];
#pragma unroll
    for (int rt = 0; rt < 4; rt++)
#pragma unroll
        for (int ks = 0; ks < 2; ks++) {
            cK[rt][ks] = *reinterpret_cast<const bf16x8*>(
                skg + stbase + (size_t)(rt * 16 + lr) * 64 + lk * 8 + ks * 32);
            cT[rt][ks] = *reinterpret_cast<const bf16x8*>(
                skTg + stbase + (size_t)(rt * 16 + lr) * 64 + lk * 8 + ks * 32);
        }
    {
        bf16x8 v0 = *reinterpret_cast<const bf16x8*>(vTb + chbase + (size_t)(c0 + vr) * QKV_STR + vt0);
        bf16x8 v1 = *reinterpret_cast<const bf16x8*>(vTb + chbase + (size_t)(c0 + vr) * QKV_STR + vt0 + 8);
        *reinterpret_cast<bf16x8*>(swz(uTL, vr, vt0 * 2))      = v0;
        *reinterpret_cast<bf16x8*>(swz(uTL, vr, vt0 * 2 + 16)) = v1;
        ikL[lane] = invk[(size_t)bh * 4096 + lane];
    }

    for (int s = 0; s < 64; s++) {
        bf16x8 nK[4][2], nT[4][2], nv0, nv1;
        float nik = 0.f;
        if (s < 63) {
            size_t vs2 = chbase + (size_t)(s + 1) * SEG;
            size_t sb2 = stbase + (size_t)(s + 1) * 4096;
#pragma unroll
            for (int rt = 0; rt < 4; rt++)
#pragma unroll
                for (int ks = 0; ks < 2; ks++) {
                    nK[rt][ks] = *reinterpret_cast<const bf16x8*>(
                        skg + sb2 + (size_t)(rt * 16 + lr) * 64 + lk * 8 + ks * 32);
                    nT[rt][ks] = *reinterpret_cast<const bf16x8*>(
                        skTg + sb2 + (size_t)(rt * 16 + lr) * 64 + lk * 8 + ks * 32);
                }
            nv0 = *reinterpret_cast<const bf16x8*>(vTb + vs2 + (size_t)(c0 + vr) * QKV_STR + vt0);
            nv1 = *reinterpret_cast<const bf16x8*>(vTb + vs2 + (size_t)(c0 + vr) * QKV_STR + vt0 + 8);
            nik = invk[(size_t)bh * 4096 + (size_t)(s + 1) * 64 + lane];
        }
        __builtin_amdgcn_sched_barrier(0);

        // MFMA1: Y = sigma(k) @ M[:, c0:c0+16]
        bf16x8 mb0 = *reinterpret_cast<const bf16x8*>(swz(MbL, lr, lk * 16));
        bf16x8 mb1 = *reinterpret_cast<const bf16x8*>(swz(MbL, lr, lk * 16 + 64));
        f32x4 Y[4];
#pragma unroll
        for (int rt = 0; rt < 4; rt++) {
            Y[rt] = (f32x4){0.f, 0.f, 0.f, 0.f};
            Y[rt] = __builtin_amdgcn_mfma_f32_16x16x32_bf16(cK[rt][0], mb0, Y[rt], 0, 0, 0);
            Y[rt] = __builtin_amdgcn_mfma_f32_16x16x32_bf16(cK[rt][1], mb1, Y[rt], 0, 0, 0);
        }

        // epilogue: u = v - Y*invk[t], in place in uTL
#pragma unroll
        for (int rt = 0; rt < 4; rt++) {
            bf16x4 vv = *reinterpret_cast<const bf16x4*>(swz(uTL, lr, rt * 32 + lk * 8));
            bf16x4 uu;
#pragma unroll
            for (int j = 0; j < 4; j++) {
                float ik = ikL[rt * 16 + lk * 4 + j];
                uu[j] = (bf16_t)((float)vv[j] - Y[rt][j] * ik);
            }
            *reinterpret_cast<bf16x4*>(swz(uTL, lr, rt * 32 + lk * 8)) = uu;
        }

        // MFMA2: M[:, c0:+16] += sigma(k)^T @ u
        bf16x8 ub0 = *reinterpret_cast<const bf16x8*>(swz(uTL, lr, lk * 16));
        bf16x8 ub1 = *reinterpret_cast<const bf16x8*>(swz(uTL, lr, lk * 16 + 64));
#pragma unroll
        for (int rt = 0; rt < 4; rt++) {
            Mreg[rt] = __builtin_amdgcn_mfma_f32_16x16x32_bf16(cT[rt][0], ub0, Mreg[rt], 0, 0, 0);
            Mreg[rt] = __builtin_amdgcn_mfma_f32_16x16x32_bf16(cT[rt][1], ub1, Mreg[rt], 0, 0, 0);
        }

        // refresh bf16 M^T slice + snapshot store (M_{s+1})
#pragma unroll
        for (int rt = 0; rt < 4; rt++) {
            bf16x4 mp;
#pragma unroll
            for (int j = 0; j < 4; j++) mp[j] = (bf16_t)Mreg[rt][j];
            *reinterpret_cast<bf16x4*>(swz(MbL, lr, rt * 32 + lk * 8)) = mp;
            if (s < 63)
                *reinterpret_cast<bf16x4*>(
                    Msnap + (((size_t)bh * 64 + s + 1) * 64 + c0 + lr) * 64 + rt * 16 + lk * 4) = mp;
        }

        if (s < 63) {
#pragma unroll
            for (int rt = 0; rt < 4; rt++)
#pragma unroll
                for (int ks = 0; ks < 2; ks++) { cK[rt][ks] = nK[rt][ks]; cT[rt][ks] = nT[rt][ks]; }
            *reinterpret_cast<bf16x8*>(swz(uTL, vr, vt0 * 2))      = nv0;
            *reinterpret_cast<bf16x8*>(swz(uTL, vr, vt0 * 2 + 16)) = nv1;
            ikL[lane] = nik;
        }
    }

    // final M slice (f32)
#pragma unroll
    for (int rt = 0; rt < 4; rt++)
#pragma unroll
        for (int j = 0; j < 4; j++)
            Mfin[(size_t)bh * 4096 + (size_t)(rt * 16 + lk * 4 + j) * 64 + c0 + lr] = Mreg[rt][j];
}

// ---------------- parallel combine: A_mem from snapshots, inline q-denominator, beta-blend ----
__global__ __launch_bounds__(256) void combine_kernel(const bf16_t* __restrict__ QKV,
                                                      const bf16_t* __restrict__ Msnap,
                                                      const bf16_t* __restrict__ Adot,
                                                      const float* __restrict__ zx,
                                                      const float* __restrict__ beta_param,
                                                      bf16_t* __restrict__ Op) {
    __shared__ bf16_t oS[64 * 72];
    __shared__ bf16_t adS[64 * 72];
    __shared__ float  iq[64];
    __shared__ float  zL[64];

    int u = blockIdx.x;
    int bh = u >> 6, s = u & 63;
    int b = bh >> 4, h = bh & 15;
    int tid = threadIdx.x;
    int w = tid >> 6, lane = tid & 63;
    int lr = lane & 15, lk = lane >> 4;
    int r = tid >> 2, c0 = (tid & 3) << 4;

    const bf16_t* qp = QKV + (size_t)(b * 4096 + s * 64) * QKV_STR + (size_t)h * 64;
    size_t vsegO = ((size_t)b * 4096 + s * 64) * 1024 + (size_t)h * 64;
    size_t sb = ((size_t)bh * 64 + s) * 4096;
    size_t ib = ((size_t)bh * 64 + s) * 64;

    float beta = 1.f / (1.f + __expf(-beta_param[h]));
    float omb = 1.f - beta;

    *reinterpret_cast<bf16x8*>(&adS[r * 72 + c0]) =
        *reinterpret_cast<const bf16x8*>(Adot + sb + (size_t)r * 64 + c0);
    *reinterpret_cast<bf16x8*>(&adS[r * 72 + c0 + 8]) =
        *reinterpret_cast<const bf16x8*>(Adot + sb + (size_t)r * 64 + c0 + 8);
    if (tid < 64) {
        zL[tid] = zx[ib + tid];
        iq[tid] = 0.f;
    }
    __syncthreads();

    f32x4 Y[4];
#pragma unroll
    for (int ct = 0; ct < 4; ct++) Y[ct] = (f32x4){0.f, 0.f, 0.f, 0.f};
    if (s > 0) {
        bf16x8 aq[2];
#pragma unroll
        for (int ks = 0; ks < 2; ks++)
            aq[ks] = sigma8(*reinterpret_cast<const bf16x8*>(
                qp + (size_t)(w * 16 + lr) * QKV_STR + lk * 8 + ks * 32));
        float dq = 0.f;
#pragma unroll
        for (int ks = 0; ks < 2; ks++)
#pragma unroll
            for (int j = 0; j < 8; j++)
                dq = __builtin_fmaf((float)aq[ks][j], zL[ks * 32 + lk * 8 + j], dq);
        dq += __shfl_xor(dq, 16);
        dq += __shfl_xor(dq, 32);
        if (lk == 0) iq[w * 16 + lr] = 1.f / (dq + 1e-6f);
#pragma unroll
        for (int ct = 0; ct < 4; ct++)
#pragma unroll
            for (int ks = 0; ks < 2; ks++) {
                bf16x8 bfrag = *reinterpret_cast<const bf16x8*>(
                    Msnap + sb + (size_t)(ct * 16 + lr) * 64 + lk * 8 + ks * 32);
                Y[ct] = __builtin_amdgcn_mfma_f32_16x16x32_bf16(aq[ks], bfrag, Y[ct], 0, 0, 0);
            }
    }
    __syncthreads();

#pragma unroll
    for (int ct = 0; ct < 4; ct++) {
        int colc = ct * 16 + lr;
#pragma unroll
        for (int j = 0; j < 4; j++) {
            int t = w * 16 + lk * 4 + j;
            float o = beta * (Y[ct][j] * iq[t]) + omb * (float)adS[t * 72 + colc];
            oS[t * 72 + colc] = (bf16_t)o;
        }
    }
    __syncthreads();

    *reinterpret_cast<bf16x8*>(Op + vsegO + (size_t)r * 1024 + c0) =
        *reinterpret_cast<const bf16x8*>(&oS[r * 72 + c0]);
    *reinterpret_cast<bf16x8*>(Op + vsegO + (size_t)r * 1024 + c0 + 8) =
        *reinterpret_cast<const bf16x8*>(&oS[r * 72 + c0 + 8]);
}

// ---------------- final means over batch ----------------
__global__ __launch_bounds__(256) void mean_kernel(const float* __restrict__ Mfin,
                                                   const float* __restrict__ zfin,
                                                   float* __restrict__ out) {
    int idx = blockIdx.x * 256 + threadIdx.x;
    if (idx < 65536) {
        out[16777216 + idx] = 0.25f * (Mfin[idx] + Mfin[idx + 65536] +
                                       Mfin[idx + 131072] + Mfin[idx + 196608]);
    } else if (idx < 66560) {
        int j = idx - 65536;
        out[16842752 + j] = 0.25f * (zfin[j] + zfin[j + 1024] + zfin[j + 2048] + zfin[j + 3072]);
    }
}

extern "C" void kernel_launch(void* const* d_in, const int* in_sizes, int n_in,
                              void* d_out, int out_size, void* d_ws, size_t ws_size,
                              hipStream_t stream) {
    const float* x      = (const float*)d_in[0];
    const float* Wq     = (const float*)d_in[1];
    const float* Wk     = (const float*)d_in[2];
    const float* Wv     = (const float*)d_in[3];
    const float* Wo     = (const float*)d_in[4];
    const float* beta_p = (const float*)d_in[5];
    float* out = (float*)d_out;
    char* ws = (char*)d_ws;

    const size_t NX = 16777216ull;

    bf16_t* xb   = (bf16_t*)ws;                         // [0, 33.5MB)
    bf16_t* Adot = xb;                                  // alias (xb dead after QKV GEMM)
    bf16_t* Wqb  = (bf16_t*)(ws + 33554432);            // Wq,Wk,Wv contiguous = [3072][1024]
    bf16_t* Wkb  = (bf16_t*)(ws + 35651584);
    bf16_t* Wvb  = (bf16_t*)(ws + 37748736);
    bf16_t* Wob  = (bf16_t*)(ws + 39845888);
    bf16_t* QKV  = (bf16_t*)(ws + 41943040);            // [16384][3072] bf16
    bf16_t* skT  = (bf16_t*)(ws + 142606336);
    bf16_t* Op   = (bf16_t*)(ws + 176160768);
    float*  csum = (float*)(ws + 209715200);
    float*  zx   = (float*)(ws + 210763776);
    float*  invk = (float*)(ws + 212860928);
    float*  Mfin = (float*)(ws + 213909504);
    float*  zfin = (float*)(ws + 214958080);
    bf16_t* Msnap = (bf16_t*)d_out;                     // d_out bf16 [0, 16.7M)  (dead until O-GEMM)
    bf16_t* skg   = (bf16_t*)d_out + 16777216;          // d_out bf16 [16.7M, 33.5M): dense sigma(k)

    cast_bf16_kernel<<<dim3(16384), dim3(256), 0, stream>>>(x, xb, (int)(NX / 4));
    cast4_kernel<<<dim3(4096), dim3(256), 0, stream>>>(Wq, Wk, Wv, Wo, Wqb, Wkb, Wvb, Wob);

    // fused QKV projection: [16384,1024] x [3072,1024]^T -> [16384,3072]
    gemm256<1><<<dim3(768), dim3(512), 0, stream>>>(xb, Wqb, (void*)QKV, 16384, 3072, 1024);

    attn_kernel<<<dim3(4096), dim3(256), 0, stream>>>(QKV, skT, skg, csum, Adot);
    zprefix_kernel<<<dim3(64), dim3(64), 0, stream>>>(csum, zx, zfin);
    denomk_kernel<<<dim3(4096), dim3(64), 0, stream>>>(skg, zx, invk);
    scan_kernel<<<dim3(256), dim3(64), 0, stream>>>(QKV, skg, skT, invk, Msnap, Mfin);
    combine_kernel<<<dim3(4096), dim3(256), 0, stream>>>(QKV, Msnap, Adot, zx, beta_p, Op);

    gemm256<0><<<dim3(256), dim3(512), 0, stream>>>(Op, Wob, d_out, 16384, 1024, 1024);
    mean_kernel<<<dim3(260), dim3(256), 0, stream>>>(Mfin, zfin, out);
}

// Round 18
// 317.073 us; speedup vs baseline: 5.4850x; 5.4850x over previous
//
#include <hip/hip_runtime.h>

typedef __bf16 bf16_t;
typedef __bf16 bf16x8 __attribute__((ext_vector_type(8)));
typedef __bf16 bf16x4 __attribute__((ext_vector_type(4)));
typedef float  f32x4  __attribute__((ext_vector_type(4)));

#define QKV_STR 3072   // fused QKV row stride (elements)

__device__ __forceinline__ void gload16(const bf16_t* g, bf16_t* l) {
    __builtin_amdgcn_global_load_lds(
        (const __attribute__((address_space(1))) void*)(g),
        (__attribute__((address_space(3))) void*)(l), 16, 0, 0);
}

// ---------------- f32 -> bf16 cast ----------------
__global__ __launch_bounds__(256) void cast_bf16_kernel(const float* __restrict__ in,
                                                        bf16_t* __restrict__ out, int n4) {
    int i = blockIdx.x * 256 + threadIdx.x;
    if (i >= n4) return;
    f32x4 v = *reinterpret_cast<const f32x4*>(in + (size_t)i * 4);
    bf16x4 o;
    o[0] = (bf16_t)v[0]; o[1] = (bf16_t)v[1]; o[2] = (bf16_t)v[2]; o[3] = (bf16_t)v[3];
    *reinterpret_cast<bf16x4*>(out + (size_t)i * 4) = o;
}

// four 1M-element weight casts in one dispatch (grid 4096)
__global__ __launch_bounds__(256) void cast4_kernel(const float* __restrict__ w0,
                                                    const float* __restrict__ w1,
                                                    const float* __restrict__ w2,
                                                    const float* __restrict__ w3,
                                                    bf16_t* __restrict__ o0,
                                                    bf16_t* __restrict__ o1,
                                                    bf16_t* __restrict__ o2,
                                                    bf16_t* __restrict__ o3) {
    int which = blockIdx.x >> 10;
    int i = (blockIdx.x & 1023) * 256 + threadIdx.x;
    const float* in = (which == 0) ? w0 : (which == 1) ? w1 : (which == 2) ? w2 : w3;
    bf16_t*     out = (which == 0) ? o0 : (which == 1) ? o1 : (which == 2) ? o2 : o3;
    f32x4 v = *reinterpret_cast<const f32x4*>(in + (size_t)i * 4);
    bf16x4 o;
    o[0] = (bf16_t)v[0]; o[1] = (bf16_t)v[1]; o[2] = (bf16_t)v[2]; o[3] = (bf16_t)v[3];
    *reinterpret_cast<bf16x4*>(out + (size_t)i * 4) = o;
}

__device__ __forceinline__ bf16x8 sigma8(bf16x8 x) {
    bf16x8 o;
#pragma unroll
    for (int j = 0; j < 8; j++) {
        float f = (float)x[j];
        float sg = f > 0.f ? f + 1.f : __expf(f);
        o[j] = (bf16_t)sg;
    }
    return o;
}

// ---------------- 256x256 GEMM, BK=32, 4-slot LDS ring, 1 barrier + counted vmcnt ----------------
template <int OUT_BF16>
__global__ __launch_bounds__(512, 2) void gemm256(const bf16_t* __restrict__ A,
                                                  const bf16_t* __restrict__ Bm,
                                                  void* __restrict__ Cv,
                                                  int M, int N, int K) {
    __shared__ bf16_t As[4][256 * 32];
    __shared__ bf16_t Bs[4][256 * 32];

    int nbn = N >> 8;
    int nwg = (M >> 8) * nbn;
    int bid = blockIdx.x;
    int wg = ((nwg & 7) == 0) ? ((bid & 7) * (nwg >> 3) + (bid >> 3)) : bid;
    int bm = wg / nbn, bn = wg % nbn;

    int tid = threadIdx.x;
    int w = tid >> 6, lane = tid & 63;
    int wm = w >> 2, wn = w & 3;
    int lr = lane & 15, lk = lane >> 4;

    int srow = lane >> 2;
    int schunk = (lane & 3) ^ ((lane >> 3) & 3);
    const bf16_t* gA0 = A  + (size_t)(bm * 256 + w * 32 + srow) * K + schunk * 8;
    const bf16_t* gA1 = gA0 + (size_t)16 * K;
    const bf16_t* gB0 = Bm + (size_t)(bn * 256 + w * 32 + srow) * K + schunk * 8;
    const bf16_t* gB1 = gB0 + (size_t)16 * K;
    int lO0 = (w * 32) * 32 + lane * 8;
    int lO1 = (w * 32 + 16) * 32 + lane * 8;

    int chunkb = (lk ^ ((lr >> 1) & 3)) << 4;
    int aoff[8], boff[4];
#pragma unroll
    for (int mi = 0; mi < 8; mi++) aoff[mi] = (wm * 128 + mi * 16 + lr) * 64 + chunkb;
#pragma unroll
    for (int ni = 0; ni < 4; ni++) boff[ni] = (wn * 64 + ni * 16 + lr) * 64 + chunkb;

    f32x4 acc[8][4];
#pragma unroll
    for (int mi = 0; mi < 8; mi++)
#pragma unroll
        for (int ni = 0; ni < 4; ni++) acc[mi][ni] = (f32x4){0.f, 0.f, 0.f, 0.f};

    const int NT = K >> 5;

    auto STAGE = [&](int t) {
        int slot = t & 3;
        size_t ko = (size_t)t * 32;
        gload16(gA0 + ko, &As[slot][lO0]);
        gload16(gA1 + ko, &As[slot][lO1]);
        gload16(gB0 + ko, &Bs[slot][lO0]);
        gload16(gB1 + ko, &Bs[slot][lO1]);
    };

    STAGE(0); STAGE(1); STAGE(2);

#pragma unroll 1
    for (int t = 0; t < NT; ++t) {
        int ahead = NT - 1 - t;
        if (ahead >= 2)      asm volatile("s_waitcnt vmcnt(8)" ::: "memory");
        else if (ahead == 1) asm volatile("s_waitcnt vmcnt(4)" ::: "memory");
        else                 asm volatile("s_waitcnt vmcnt(0)" ::: "memory");
        __builtin_amdgcn_sched_barrier(0);
        __builtin_amdgcn_s_barrier();
        __builtin_amdgcn_sched_barrier(0);

        const char* pa = (const char*)(&As[t & 3][0]);
        const char* pb = (const char*)(&Bs[t & 3][0]);
        bf16x8 af[8], bfr[4];
#pragma unroll
        for (int ni = 0; ni < 4; ni++)
            bfr[ni] = *reinterpret_cast<const bf16x8*>(pb + boff[ni]);
#pragma unroll
        for (int mi = 0; mi < 8; mi++)
            af[mi] = *reinterpret_cast<const bf16x8*>(pa + aoff[mi]);

        if (t + 3 < NT) STAGE(t + 3);

        __builtin_amdgcn_s_setprio(1);
#pragma unroll
        for (int mi = 0; mi < 8; mi++)
#pragma unroll
            for (int ni = 0; ni < 4; ni++)
                acc[mi][ni] = __builtin_amdgcn_mfma_f32_16x16x32_bf16(af[mi], bfr[ni], acc[mi][ni], 0, 0, 0);
        __builtin_amdgcn_s_setprio(0);
    }

    int row0 = bm * 256 + wm * 128 + lk * 4;
    int col0 = bn * 256 + wn * 64 + lr;
#pragma unroll
    for (int mi = 0; mi < 8; mi++)
#pragma unroll
        for (int ni = 0; ni < 4; ni++)
#pragma unroll
            for (int jj = 0; jj < 4; jj++) {
                size_t idx = (size_t)(row0 + mi * 16 + jj) * N + (col0 + ni * 16);
                float v = acc[mi][ni][jj];
                if (OUT_BF16) reinterpret_cast<bf16_t*>(Cv)[idx] = (bf16_t)v;
                else          reinterpret_cast<float*>(Cv)[idx]  = v;
            }
}

// ---------------- parallel local attention on fused QKV (row stride 3072) ----------------
// Emits: sigma(k) DENSE -> skg; sigma(k)^T dense -> skTg; v^T in-place over V cols;
// column sums; A_dot.
__global__ __launch_bounds__(256) void attn_kernel(bf16_t* __restrict__ QKV,
                                                   bf16_t* __restrict__ skTg,
                                                   bf16_t* __restrict__ skg,
                                                   float* __restrict__ csum,
                                                   bf16_t* __restrict__ Adot) {
    __shared__ bf16_t kS[64 * 72];
    __shared__ bf16_t vS[64 * 72];
    __shared__ bf16_t skT[64 * 72];
    __shared__ bf16_t vT[64 * 72];
    __shared__ bf16_t pS[64 * 72];
    __shared__ float  scr[64 * 68];

    int u = blockIdx.x;
    int bh = u >> 6, s = u & 63;
    int b = bh >> 4, h = bh & 15;
    int tid = threadIdx.x;
    int w = tid >> 6, lane = tid & 63;
    int lr = lane & 15, lk = lane >> 4;
    int r = tid >> 2, qd = tid & 3, c0 = qd << 4;

    bf16_t* qp = QKV + (size_t)(b * 4096 + s * 64) * QKV_STR + (size_t)h * 64;
    bf16_t* kp = qp + 1024;
    bf16_t* vp = qp + 2048;
    size_t sb = ((size_t)bh * 64 + s) * 4096;

    {
        bf16x8 k0 = *reinterpret_cast<const bf16x8*>(kp + (size_t)r * QKV_STR + c0);
        bf16x8 k1 = *reinterpret_cast<const bf16x8*>(kp + (size_t)r * QKV_STR + c0 + 8);
        bf16x8 v0 = *reinterpret_cast<const bf16x8*>(vp + (size_t)r * QKV_STR + c0);
        bf16x8 v1 = *reinterpret_cast<const bf16x8*>(vp + (size_t)r * QKV_STR + c0 + 8);
        *reinterpret_cast<bf16x8*>(&kS[r * 72 + c0])     = k0;
        *reinterpret_cast<bf16x8*>(&kS[r * 72 + c0 + 8]) = k1;
        *reinterpret_cast<bf16x8*>(&vS[r * 72 + c0])     = v0;
        *reinterpret_cast<bf16x8*>(&vS[r * 72 + c0 + 8]) = v1;
        bf16x8 s0 = sigma8(k0), s1 = sigma8(k1);
        *reinterpret_cast<bf16x8*>(skg + sb + (size_t)r * 64 + c0)     = s0;
        *reinterpret_cast<bf16x8*>(skg + sb + (size_t)r * 64 + c0 + 8) = s1;
#pragma unroll
        for (int j = 0; j < 8; j++) {
            skT[(c0 + j) * 72 + r]     = s0[j];
            skT[(c0 + 8 + j) * 72 + r] = s1[j];
            vT[(c0 + j) * 72 + r]      = v0[j];
            vT[(c0 + 8 + j) * 72 + r]  = v1[j];
        }
    }
    __syncthreads();

    if (tid < 64) {
        float acc = 0.f;
#pragma unroll 8
        for (int t = 0; t < 64; t++) acc += (float)skT[tid * 72 + t];
        csum[((size_t)bh * 64 + s) * 64 + tid] = acc;
    }
    *reinterpret_cast<bf16x8*>(skTg + sb + (size_t)r * 64 + c0) =
        *reinterpret_cast<const bf16x8*>(&skT[r * 72 + c0]);
    *reinterpret_cast<bf16x8*>(skTg + sb + (size_t)r * 64 + c0 + 8) =
        *reinterpret_cast<const bf16x8*>(&skT[r * 72 + c0 + 8]);
    *reinterpret_cast<bf16x8*>(vp + (size_t)r * QKV_STR + c0) =
        *reinterpret_cast<const bf16x8*>(&vT[r * 72 + c0]);
    *reinterpret_cast<bf16x8*>(vp + (size_t)r * QKV_STR + c0 + 8) =
        *reinterpret_cast<const bf16x8*>(&vT[r * 72 + c0 + 8]);

    {
        bf16x8 aq[2];
#pragma unroll
        for (int ks = 0; ks < 2; ks++)
            aq[ks] = *reinterpret_cast<const bf16x8*>(qp + (size_t)(w * 16 + lr) * QKV_STR + lk * 8 + ks * 32);
        f32x4 sc[4];
#pragma unroll
        for (int ct = 0; ct < 4; ct++) {
            sc[ct] = (f32x4){0.f, 0.f, 0.f, 0.f};
#pragma unroll
            for (int ks = 0; ks < 2; ks++) {
                bf16x8 bfrag = *reinterpret_cast<const bf16x8*>(&kS[(ct * 16 + lr) * 72 + lk * 8 + ks * 32]);
                sc[ct] = __builtin_amdgcn_mfma_f32_16x16x32_bf16(aq[ks], bfrag, sc[ct], 0, 0, 0);
            }
        }
#pragma unroll
        for (int ct = 0; ct < 4; ct++)
#pragma unroll
            for (int j = 0; j < 4; j++)
                scr[(w * 16 + lk * 4 + j) * 68 + ct * 16 + lr] = sc[ct][j] * 0.125f;
    }
    __syncthreads();

    {
        float p[16];
        float mx = -3.4e38f;
        const float* srow_p = &scr[r * 68 + c0];
#pragma unroll
        for (int i = 0; i < 16; i++) {
            int c = c0 + i;
            float v = (c <= r) ? srow_p[i] : -3.4e38f;
            p[i] = v;
            mx = fmaxf(mx, v);
        }
        mx = fmaxf(mx, __shfl_xor(mx, 1));
        mx = fmaxf(mx, __shfl_xor(mx, 2));
        float sum = 0.f;
#pragma unroll
        for (int i = 0; i < 16; i++) {
            int c = c0 + i;
            float e = (c <= r) ? __expf(p[i] - mx) : 0.f;
            p[i] = e;
            sum += e;
        }
        sum += __shfl_xor(sum, 1);
        sum += __shfl_xor(sum, 2);
        float inv = 1.f / sum;
        bf16x8 p0, p1;
#pragma unroll
        for (int j = 0; j < 8; j++) {
            p0[j] = (bf16_t)(p[j] * inv);
            p1[j] = (bf16_t)(p[8 + j] * inv);
        }
        *reinterpret_cast<bf16x8*>(&pS[r * 72 + c0])     = p0;
        *reinterpret_cast<bf16x8*>(&pS[r * 72 + c0 + 8]) = p1;
    }
    __syncthreads();

    {
        f32x4 ad[4];
#pragma unroll
        for (int ct = 0; ct < 4; ct++) {
            ad[ct] = (f32x4){0.f, 0.f, 0.f, 0.f};
#pragma unroll
            for (int ks = 0; ks < 2; ks++) {
                bf16x8 afrag = *reinterpret_cast<const bf16x8*>(&pS[(w * 16 + lr) * 72 + lk * 8 + ks * 32]);
                bf16x8 bfrag = *reinterpret_cast<const bf16x8*>(&vT[(ct * 16 + lr) * 72 + lk * 8 + ks * 32]);
                ad[ct] = __builtin_amdgcn_mfma_f32_16x16x32_bf16(afrag, bfrag, ad[ct], 0, 0, 0);
            }
        }
#pragma unroll
        for (int ct = 0; ct < 4; ct++)
#pragma unroll
            for (int j = 0; j < 4; j++)
                kS[(w * 16 + lk * 4 + j) * 72 + ct * 16 + lr] = (bf16_t)ad[ct][j];
    }
    __syncthreads();
    *reinterpret_cast<bf16x8*>(Adot + sb + (size_t)r * 64 + c0) =
        *reinterpret_cast<const bf16x8*>(&kS[r * 72 + c0]);
    *reinterpret_cast<bf16x8*>(Adot + sb + (size_t)r * 64 + c0 + 8) =
        *reinterpret_cast<const bf16x8*>(&kS[r * 72 + c0 + 8]);
}

// ---------------- z prefix over segments (batched loads, register prefix) ----------------
__global__ __launch_bounds__(64) void zprefix_kernel(const float* __restrict__ csum,
                                                     float* __restrict__ zx,
                                                     float* __restrict__ zfin) {
    int bh = blockIdx.x;
    int d = threadIdx.x;
    float c[64];
#pragma unroll
    for (int s = 0; s < 64; s++)
        c[s] = csum[((size_t)bh * 64 + s) * 64 + d];
    float z = 0.f;
#pragma unroll
    for (int s = 0; s < 64; s++) {
        zx[((size_t)bh * 64 + s) * 64 + d] = z;
        z += c[s];
    }
    zfin[bh * 64 + d] = z;
}

// ---------------- k-side denominators only: 1/(sigma(k) . z + eps) (dense sigma(k)) -------
__global__ __launch_bounds__(64) void denomk_kernel(const bf16_t* __restrict__ skg,
                                                    const float* __restrict__ zx,
                                                    float* __restrict__ invk) {
    __shared__ float zL[64];
    int u = blockIdx.x;
    int tid = threadIdx.x;
    zL[tid] = zx[(size_t)u * 64 + tid];
    __syncthreads();
    const bf16_t* src = skg + (size_t)u * 4096 + (size_t)tid * 64;
    float acc = 0.f;
#pragma unroll
    for (int blk = 0; blk < 8; blk++) {
        bf16x8 v = *reinterpret_cast<const bf16x8*>(src + blk * 8);
#pragma unroll
        for (int j = 0; j < 8; j++)
            acc = __builtin_fmaf((float)v[j], zL[blk * 8 + j], acc);
    }
    invk[(size_t)u * 64 + tid] = 1.f / (acc + 1e-6f);
}

// ---------------- k-side recurrence scan: 1 wave per block, no barriers, depth-1 prefetch ----
// grid 256: bh = blk & 63, cq = blk >> 6 (column quarter). M cols c0..c0+15 per block.
__global__ __launch_bounds__(64, 1) void scan_kernel(const bf16_t* __restrict__ QKV,
                                                     const bf16_t* __restrict__ skg,
                                                     const bf16_t* __restrict__ skTg,
                                                     const float* __restrict__ invk,
                                                     bf16_t* __restrict__ Msnap,
                                                     float* __restrict__ Mfin) {
    __shared__ bf16_t MbL[16 * 72];  // M^T slice (swizzled rows)
    __shared__ bf16_t uTL[16 * 72];  // v^T -> u^T slice (swizzled)
    __shared__ float  ikL[64];

    int blk = blockIdx.x;
    int bh = blk & 63, cq = blk >> 6;
    int c0 = cq << 4;
    int b = bh >> 4, h = bh & 15;
    int lane = threadIdx.x;
    int lr = lane & 15, lk = lane >> 4;
    int vr = lane >> 2, vt0 = (lane & 3) << 4;

    const bf16_t* vTb = QKV + 2048;
    size_t chbase = (size_t)(b * 4096) * QKV_STR + (size_t)h * 64;
    size_t stbase = (size_t)bh * 64 * 4096;
    const size_t SEG = (size_t)64 * QKV_STR;

    auto swz = [](bf16_t* base, int row, int intra) -> bf16_t* {
        return (bf16_t*)((char*)base + row * 144 + (intra ^ ((row & 7) << 4)));
    };

    for (int i = lane; i < 16 * 72; i += 64) MbL[i] = (bf16_t)0.f;
    f32x4 Mreg[4];
#pragma unroll
    for (int rt = 0; rt < 4; rt++) Mreg[rt] = (f32x4){0.f, 0.f, 0.f, 0.f};

    bf16x8 cK[4][2], cT[4][2];
#pragma unroll
    for (int rt = 0; rt < 4; rt++)
#pragma unroll
        for (int ks = 0; ks < 2; ks++) {
            cK[rt][ks] = *reinterpret_cast<const bf16x8*>(
                skg + stbase + (size_t)(rt * 16 + lr) * 64 + lk * 8 + ks * 32);
            cT[rt][ks] = *reinterpret_cast<const bf16x8*>(
                skTg + stbase + (size_t)(rt * 16 + lr) * 64 + lk * 8 + ks * 32);
        }
    {
        bf16x8 v0 = *reinterpret_cast<const bf16x8*>(vTb + chbase + (size_t)(c0 + vr) * QKV_STR + vt0);
        bf16x8 v1 = *reinterpret_cast<const bf16x8*>(vTb + chbase + (size_t)(c0 + vr) * QKV_STR + vt0 + 8);
        *reinterpret_cast<bf16x8*>(swz(uTL, vr, vt0 * 2))      = v0;
        *reinterpret_cast<bf16x8*>(swz(uTL, vr, vt0 * 2 + 16)) = v1;
        ikL[lane] = invk[(size_t)bh * 4096 + lane];
    }

    for (int s = 0; s < 64; s++) {
        bf16x8 nK[4][2], nT[4][2], nv0, nv1;
        float nik = 0.f;
        if (s < 63) {
            size_t vs2 = chbase + (size_t)(s + 1) * SEG;
            size_t sb2 = stbase + (size_t)(s + 1) * 4096;
#pragma unroll
            for (int rt = 0; rt < 4; rt++)
#pragma unroll
                for (int ks = 0; ks < 2; ks++) {
                    nK[rt][ks] = *reinterpret_cast<const bf16x8*>(
                        skg + sb2 + (size_t)(rt * 16 + lr) * 64 + lk * 8 + ks * 32);
                    nT[rt][ks] = *reinterpret_cast<const bf16x8*>(
                        skTg + sb2 + (size_t)(rt * 16 + lr) * 64 + lk * 8 + ks * 32);
                }
            nv0 = *reinterpret_cast<const bf16x8*>(vTb + vs2 + (size_t)(c0 + vr) * QKV_STR + vt0);
            nv1 = *reinterpret_cast<const bf16x8*>(vTb + vs2 + (size_t)(c0 + vr) * QKV_STR + vt0 + 8);
            nik = invk[(size_t)bh * 4096 + (size_t)(s + 1) * 64 + lane];
        }
        __builtin_amdgcn_sched_barrier(0);

        // MFMA1: Y = sigma(k) @ M[:, c0:c0+16]
        bf16x8 mb0 = *reinterpret_cast<const bf16x8*>(swz(MbL, lr, lk * 16));
        bf16x8 mb1 = *reinterpret_cast<const bf16x8*>(swz(MbL, lr, lk * 16 + 64));
        f32x4 Y[4];
#pragma unroll
        for (int rt = 0; rt < 4; rt++) {
            Y[rt] = (f32x4){0.f, 0.f, 0.f, 0.f};
            Y[rt] = __builtin_amdgcn_mfma_f32_16x16x32_bf16(cK[rt][0], mb0, Y[rt], 0, 0, 0);
            Y[rt] = __builtin_amdgcn_mfma_f32_16x16x32_bf16(cK[rt][1], mb1, Y[rt], 0, 0, 0);
        }

        // epilogue: u = v - Y*invk[t], in place in uTL
#pragma unroll
        for (int rt = 0; rt < 4; rt++) {
            bf16x4 vv = *reinterpret_cast<const bf16x4*>(swz(uTL, lr, rt * 32 + lk * 8));
            bf16x4 uu;
#pragma unroll
            for (int j = 0; j < 4; j++) {
                float ik = ikL[rt * 16 + lk * 4 + j];
                uu[j] = (bf16_t)((float)vv[j] - Y[rt][j] * ik);
            }
            *reinterpret_cast<bf16x4*>(swz(uTL, lr, rt * 32 + lk * 8)) = uu;
        }

        // MFMA2: M[:, c0:+16] += sigma(k)^T @ u
        bf16x8 ub0 = *reinterpret_cast<const bf16x8*>(swz(uTL, lr, lk * 16));
        bf16x8 ub1 = *reinterpret_cast<const bf16x8*>(swz(uTL, lr, lk * 16 + 64));
#pragma unroll
        for (int rt = 0; rt < 4; rt++) {
            Mreg[rt] = __builtin_amdgcn_mfma_f32_16x16x32_bf16(cT[rt][0], ub0, Mreg[rt], 0, 0, 0);
            Mreg[rt] = __builtin_amdgcn_mfma_f32_16x16x32_bf16(cT[rt][1], ub1, Mreg[rt], 0, 0, 0);
        }

        // refresh bf16 M^T slice + snapshot store (M_{s+1})
#pragma unroll
        for (int rt = 0; rt < 4; rt++) {
            bf16x4 mp;
#pragma unroll
            for (int j = 0; j < 4; j++) mp[j] = (bf16_t)Mreg[rt][j];
            *reinterpret_cast<bf16x4*>(swz(MbL, lr, rt * 32 + lk * 8)) = mp;
            if (s < 63)
                *reinterpret_cast<bf16x4*>(
                    Msnap + (((size_t)bh * 64 + s + 1) * 64 + c0 + lr) * 64 + rt * 16 + lk * 4) = mp;
        }

        if (s < 63) {
#pragma unroll
            for (int rt = 0; rt < 4; rt++)
#pragma unroll
                for (int ks = 0; ks < 2; ks++) { cK[rt][ks] = nK[rt][ks]; cT[rt][ks] = nT[rt][ks]; }
            *reinterpret_cast<bf16x8*>(swz(uTL, vr, vt0 * 2))      = nv0;
            *reinterpret_cast<bf16x8*>(swz(uTL, vr, vt0 * 2 + 16)) = nv1;
            ikL[lane] = nik;
        }
    }

    // final M slice (f32)
#pragma unroll
    for (int rt = 0; rt < 4; rt++)
#pragma unroll
        for (int j = 0; j < 4; j++)
            Mfin[(size_t)bh * 4096 + (size_t)(rt * 16 + lk * 4 + j) * 64 + c0 + lr] = Mreg[rt][j];
}

// ---------------- parallel combine: A_mem from snapshots, inline q-denominator, beta-blend ----
__global__ __launch_bounds__(256) void combine_kernel(const bf16_t* __restrict__ QKV,
                                                      const bf16_t* __restrict__ Msnap,
                                                      const bf16_t* __restrict__ Adot,
                                                      const float* __restrict__ zx,
                                                      const float* __restrict__ beta_param,
                                                      bf16_t* __restrict__ Op) {
    __shared__ bf16_t oS[64 * 72];
    __shared__ bf16_t adS[64 * 72];
    __shared__ float  iq[64];
    __shared__ float  zL[64];

    int u = blockIdx.x;
    int bh = u >> 6, s = u & 63;
    int b = bh >> 4, h = bh & 15;
    int tid = threadIdx.x;
    int w = tid >> 6, lane = tid & 63;
    int lr = lane & 15, lk = lane >> 4;
    int r = tid >> 2, c0 = (tid & 3) << 4;

    const bf16_t* qp = QKV + (size_t)(b * 4096 + s * 64) * QKV_STR + (size_t)h * 64;
    size_t vsegO = ((size_t)b * 4096 + s * 64) * 1024 + (size_t)h * 64;
    size_t sb = ((size_t)bh * 64 + s) * 4096;
    size_t ib = ((size_t)bh * 64 + s) * 64;

    float beta = 1.f / (1.f + __expf(-beta_param[h]));
    float omb = 1.f - beta;

    *reinterpret_cast<bf16x8*>(&adS[r * 72 + c0]) =
        *reinterpret_cast<const bf16x8*>(Adot + sb + (size_t)r * 64 + c0);
    *reinterpret_cast<bf16x8*>(&adS[r * 72 + c0 + 8]) =
        *reinterpret_cast<const bf16x8*>(Adot + sb + (size_t)r * 64 + c0 + 8);
    if (tid < 64) {
        zL[tid] = zx[ib + tid];
        iq[tid] = 0.f;
    }
    __syncthreads();

    f32x4 Y[4];
#pragma unroll
    for (int ct = 0; ct < 4; ct++) Y[ct] = (f32x4){0.f, 0.f, 0.f, 0.f};
    if (s > 0) {
        bf16x8 aq[2];
#pragma unroll
        for (int ks = 0; ks < 2; ks++)
            aq[ks] = sigma8(*reinterpret_cast<const bf16x8*>(
                qp + (size_t)(w * 16 + lr) * QKV_STR + lk * 8 + ks * 32));
        float dq = 0.f;
#pragma unroll
        for (int ks = 0; ks < 2; ks++)
#pragma unroll
            for (int j = 0; j < 8; j++)
                dq = __builtin_fmaf((float)aq[ks][j], zL[ks * 32 + lk * 8 + j], dq);
        dq += __shfl_xor(dq, 16);
        dq += __shfl_xor(dq, 32);
        if (lk == 0) iq[w * 16 + lr] = 1.f / (dq + 1e-6f);
#pragma unroll
        for (int ct = 0; ct < 4; ct++)
#pragma unroll
            for (int ks = 0; ks < 2; ks++) {
                bf16x8 bfrag = *reinterpret_cast<const bf16x8*>(
                    Msnap + sb + (size_t)(ct * 16 + lr) * 64 + lk * 8 + ks * 32);
                Y[ct] = __builtin_amdgcn_mfma_f32_16x16x32_bf16(aq[ks], bfrag, Y[ct], 0, 0, 0);
            }
    }
    __syncthreads();

#pragma unroll
    for (int ct = 0; ct < 4; ct++) {
        int colc = ct * 16 + lr;
#pragma unroll
        for (int j = 0; j < 4; j++) {
            int t = w * 16 + lk * 4 + j;
            float o = beta * (Y[ct][j] * iq[t]) + omb * (float)adS[t * 72 + colc];
            oS[t * 72 + colc] = (bf16_t)o;
        }
    }
    __syncthreads();

    *reinterpret_cast<bf16x8*>(Op + vsegO + (size_t)r * 1024 + c0) =
        *reinterpret_cast<const bf16x8*>(&oS[r * 72 + c0]);
    *reinterpret_cast<bf16x8*>(Op + vsegO + (size_t)r * 1024 + c0 + 8) =
        *reinterpret_cast<const bf16x8*>(&oS[r * 72 + c0 + 8]);
}

// ---------------- final means over batch ----------------
__global__ __launch_bounds__(256) void mean_kernel(const float* __restrict__ Mfin,
                                                   const float* __restrict__ zfin,
                                                   float* __restrict__ out) {
    int idx = blockIdx.x * 256 + threadIdx.x;
    if (idx < 65536) {
        out[16777216 + idx] = 0.25f * (Mfin[idx] + Mfin[idx + 65536] +
                                       Mfin[idx + 131072] + Mfin[idx + 196608]);
    } else if (idx < 66560) {
        int j = idx - 65536;
        out[16842752 + j] = 0.25f * (zfin[j] + zfin[j + 1024] + zfin[j + 2048] + zfin[j + 3072]);
    }
}

extern "C" void kernel_launch(void* const* d_in, const int* in_sizes, int n_in,
                              void* d_out, int out_size, void* d_ws, size_t ws_size,
                              hipStream_t stream) {
    const float* x      = (const float*)d_in[0];
    const float* Wq     = (const float*)d_in[1];
    const float* Wk     = (const float*)d_in[2];
    const float* Wv     = (const float*)d_in[3];
    const float* Wo     = (const float*)d_in[4];
    const float* beta_p = (const float*)d_in[5];
    float* out = (float*)d_out;
    char* ws = (char*)d_ws;

    const size_t NX = 16777216ull;

    bf16_t* xb   = (bf16_t*)ws;                         // [0, 33.5MB)
    bf16_t* Adot = xb;                                  // alias (xb dead after QKV GEMM)
    bf16_t* Wqb  = (bf16_t*)(ws + 33554432);            // Wq,Wk,Wv contiguous = [3072][1024]
    bf16_t* Wkb  = (bf16_t*)(ws + 35651584);
    bf16_t* Wvb  = (bf16_t*)(ws + 37748736);
    bf16_t* Wob  = (bf16_t*)(ws + 39845888);
    bf16_t* QKV  = (bf16_t*)(ws + 41943040);            // [16384][3072] bf16
    bf16_t* skT  = (bf16_t*)(ws + 142606336);
    bf16_t* Op   = (bf16_t*)(ws + 176160768);
    float*  csum = (float*)(ws + 209715200);
    float*  zx   = (float*)(ws + 210763776);
    float*  invk = (float*)(ws + 212860928);
    float*  Mfin = (float*)(ws + 213909504);
    float*  zfin = (float*)(ws + 214958080);
    bf16_t* Msnap = (bf16_t*)d_out;                     // d_out bf16 [0, 16.7M)  (dead until O-GEMM)
    bf16_t* skg   = (bf16_t*)d_out + 16777216;          // d_out bf16 [16.7M, 33.5M): dense sigma(k)

    cast_bf16_kernel<<<dim3(16384), dim3(256), 0, stream>>>(x, xb, (int)(NX / 4));
    cast4_kernel<<<dim3(4096), dim3(256), 0, stream>>>(Wq, Wk, Wv, Wo, Wqb, Wkb, Wvb, Wob);

    // fused QKV projection: [16384,1024] x [3072,1024]^T -> [16384,3072]
    gemm256<1><<<dim3(768), dim3(512), 0, stream>>>(xb, Wqb, (void*)QKV, 16384, 3072, 1024);

    attn_kernel<<<dim3(4096), dim3(256), 0, stream>>>(QKV, skT, skg, csum, Adot);
    zprefix_kernel<<<dim3(64), dim3(64), 0, stream>>>(csum, zx, zfin);
    denomk_kernel<<<dim3(4096), dim3(64), 0, stream>>>(skg, zx, invk);
    scan_kernel<<<dim3(256), dim3(64), 0, stream>>>(QKV, skg, skT, invk, Msnap, Mfin);
    combine_kernel<<<dim3(4096), dim3(256), 0, stream>>>(QKV, Msnap, Adot, zx, beta_p, Op);

    gemm256<0><<<dim3(256), dim3(512), 0, stream>>>(Op, Wob, d_out, 16384, 1024, 1024);
    mean_kernel<<<dim3(260), dim3(256), 0, stream>>>(Mfin, zfin, out);
}

// Round 19
// 314.360 us; speedup vs baseline: 5.5323x; 1.0086x over previous
//
#include <hip/hip_runtime.h>

typedef __bf16 bf16_t;
typedef __bf16 bf16x8 __attribute__((ext_vector_type(8)));
typedef __bf16 bf16x4 __attribute__((ext_vector_type(4)));
typedef float  f32x4  __attribute__((ext_vector_type(4)));

#define QKV_STR 3072   // fused QKV row stride (elements)

__device__ __forceinline__ void gload16(const bf16_t* g, bf16_t* l) {
    __builtin_amdgcn_global_load_lds(
        (const __attribute__((address_space(1))) void*)(g),
        (__attribute__((address_space(3))) void*)(l), 16, 0, 0);
}

// ---------------- all f32 -> bf16 casts in one dispatch ----------------
// blocks [0, 16384): x (16.7M elems). blocks [16384, 20480): Wq,Wk,Wv,Wo (1M each).
__global__ __launch_bounds__(256) void cast_all_kernel(const float* __restrict__ x,
                                                       const float* __restrict__ w0,
                                                       const float* __restrict__ w1,
                                                       const float* __restrict__ w2,
                                                       const float* __restrict__ w3,
                                                       bf16_t* __restrict__ xo,
                                                       bf16_t* __restrict__ o0,
                                                       bf16_t* __restrict__ o1,
                                                       bf16_t* __restrict__ o2,
                                                       bf16_t* __restrict__ o3) {
    int blk = blockIdx.x;
    const float* in;
    bf16_t* out;
    int i;
    if (blk < 16384) {
        in = x; out = xo;
        i = blk * 256 + threadIdx.x;
    } else {
        int wb = blk - 16384;
        int which = wb >> 10;
        in  = (which == 0) ? w0 : (which == 1) ? w1 : (which == 2) ? w2 : w3;
        out = (which == 0) ? o0 : (which == 1) ? o1 : (which == 2) ? o2 : o3;
        i = (wb & 1023) * 256 + threadIdx.x;
    }
    f32x4 v = *reinterpret_cast<const f32x4*>(in + (size_t)i * 4);
    bf16x4 o;
    o[0] = (bf16_t)v[0]; o[1] = (bf16_t)v[1]; o[2] = (bf16_t)v[2]; o[3] = (bf16_t)v[3];
    *reinterpret_cast<bf16x4*>(out + (size_t)i * 4) = o;
}

__device__ __forceinline__ bf16x8 sigma8(bf16x8 x) {
    bf16x8 o;
#pragma unroll
    for (int j = 0; j < 8; j++) {
        float f = (float)x[j];
        float sg = f > 0.f ? f + 1.f : __expf(f);
        o[j] = (bf16_t)sg;
    }
    return o;
}

// ---------------- 256x256 GEMM, BK=32, 4-slot LDS ring, 1 barrier + counted vmcnt ----------------
template <int OUT_BF16>
__global__ __launch_bounds__(512, 2) void gemm256(const bf16_t* __restrict__ A,
                                                  const bf16_t* __restrict__ Bm,
                                                  void* __restrict__ Cv,
                                                  int M, int N, int K) {
    __shared__ bf16_t As[4][256 * 32];
    __shared__ bf16_t Bs[4][256 * 32];

    int nbn = N >> 8;
    int nwg = (M >> 8) * nbn;
    int bid = blockIdx.x;
    int wg = ((nwg & 7) == 0) ? ((bid & 7) * (nwg >> 3) + (bid >> 3)) : bid;
    int bm = wg / nbn, bn = wg % nbn;

    int tid = threadIdx.x;
    int w = tid >> 6, lane = tid & 63;
    int wm = w >> 2, wn = w & 3;
    int lr = lane & 15, lk = lane >> 4;

    int srow = lane >> 2;
    int schunk = (lane & 3) ^ ((lane >> 3) & 3);
    const bf16_t* gA0 = A  + (size_t)(bm * 256 + w * 32 + srow) * K + schunk * 8;
    const bf16_t* gA1 = gA0 + (size_t)16 * K;
    const bf16_t* gB0 = Bm + (size_t)(bn * 256 + w * 32 + srow) * K + schunk * 8;
    const bf16_t* gB1 = gB0 + (size_t)16 * K;
    int lO0 = (w * 32) * 32 + lane * 8;
    int lO1 = (w * 32 + 16) * 32 + lane * 8;

    int chunkb = (lk ^ ((lr >> 1) & 3)) << 4;
    int aoff[8], boff[4];
#pragma unroll
    for (int mi = 0; mi < 8; mi++) aoff[mi] = (wm * 128 + mi * 16 + lr) * 64 + chunkb;
#pragma unroll
    for (int ni = 0; ni < 4; ni++) boff[ni] = (wn * 64 + ni * 16 + lr) * 64 + chunkb;

    f32x4 acc[8][4];
#pragma unroll
    for (int mi = 0; mi < 8; mi++)
#pragma unroll
        for (int ni = 0; ni < 4; ni++) acc[mi][ni] = (f32x4){0.f, 0.f, 0.f, 0.f};

    const int NT = K >> 5;

    auto STAGE = [&](int t) {
        int slot = t & 3;
        size_t ko = (size_t)t * 32;
        gload16(gA0 + ko, &As[slot][lO0]);
        gload16(gA1 + ko, &As[slot][lO1]);
        gload16(gB0 + ko, &Bs[slot][lO0]);
        gload16(gB1 + ko, &Bs[slot][lO1]);
    };

    STAGE(0); STAGE(1); STAGE(2);

#pragma unroll 1
    for (int t = 0; t < NT; ++t) {
        int ahead = NT - 1 - t;
        if (ahead >= 2)      asm volatile("s_waitcnt vmcnt(8)" ::: "memory");
        else if (ahead == 1) asm volatile("s_waitcnt vmcnt(4)" ::: "memory");
        else                 asm volatile("s_waitcnt vmcnt(0)" ::: "memory");
        __builtin_amdgcn_sched_barrier(0);
        __builtin_amdgcn_s_barrier();
        __builtin_amdgcn_sched_barrier(0);

        const char* pa = (const char*)(&As[t & 3][0]);
        const char* pb = (const char*)(&Bs[t & 3][0]);
        bf16x8 af[8], bfr[4];
#pragma unroll
        for (int ni = 0; ni < 4; ni++)
            bfr[ni] = *reinterpret_cast<const bf16x8*>(pb + boff[ni]);
#pragma unroll
        for (int mi = 0; mi < 8; mi++)
            af[mi] = *reinterpret_cast<const bf16x8*>(pa + aoff[mi]);

        if (t + 3 < NT) STAGE(t + 3);

        __builtin_amdgcn_s_setprio(1);
#pragma unroll
        for (int mi = 0; mi < 8; mi++)
#pragma unroll
            for (int ni = 0; ni < 4; ni++)
                acc[mi][ni] = __builtin_amdgcn_mfma_f32_16x16x32_bf16(af[mi], bfr[ni], acc[mi][ni], 0, 0, 0);
        __builtin_amdgcn_s_setprio(0);
    }

    int row0 = bm * 256 + wm * 128 + lk * 4;
    int col0 = bn * 256 + wn * 64 + lr;
#pragma unroll
    for (int mi = 0; mi < 8; mi++)
#pragma unroll
        for (int ni = 0; ni < 4; ni++)
#pragma unroll
            for (int jj = 0; jj < 4; jj++) {
                size_t idx = (size_t)(row0 + mi * 16 + jj) * N + (col0 + ni * 16);
                float v = acc[mi][ni][jj];
                if (OUT_BF16) reinterpret_cast<bf16_t*>(Cv)[idx] = (bf16_t)v;
                else          reinterpret_cast<float*>(Cv)[idx]  = v;
            }
}

// ---------------- parallel local attention on fused QKV (row stride 3072) ----------------
__global__ __launch_bounds__(256) void attn_kernel(bf16_t* __restrict__ QKV,
                                                   bf16_t* __restrict__ skTg,
                                                   bf16_t* __restrict__ skg,
                                                   float* __restrict__ csum,
                                                   bf16_t* __restrict__ Adot) {
    __shared__ bf16_t kS[64 * 72];
    __shared__ bf16_t vS[64 * 72];
    __shared__ bf16_t skT[64 * 72];
    __shared__ bf16_t vT[64 * 72];
    __shared__ bf16_t pS[64 * 72];
    __shared__ float  scr[64 * 68];

    int u = blockIdx.x;
    int bh = u >> 6, s = u & 63;
    int b = bh >> 4, h = bh & 15;
    int tid = threadIdx.x;
    int w = tid >> 6, lane = tid & 63;
    int lr = lane & 15, lk = lane >> 4;
    int r = tid >> 2, qd = tid & 3, c0 = qd << 4;

    bf16_t* qp = QKV + (size_t)(b * 4096 + s * 64) * QKV_STR + (size_t)h * 64;
    bf16_t* kp = qp + 1024;
    bf16_t* vp = qp + 2048;
    size_t sb = ((size_t)bh * 64 + s) * 4096;

    {
        bf16x8 k0 = *reinterpret_cast<const bf16x8*>(kp + (size_t)r * QKV_STR + c0);
        bf16x8 k1 = *reinterpret_cast<const bf16x8*>(kp + (size_t)r * QKV_STR + c0 + 8);
        bf16x8 v0 = *reinterpret_cast<const bf16x8*>(vp + (size_t)r * QKV_STR + c0);
        bf16x8 v1 = *reinterpret_cast<const bf16x8*>(vp + (size_t)r * QKV_STR + c0 + 8);
        *reinterpret_cast<bf16x8*>(&kS[r * 72 + c0])     = k0;
        *reinterpret_cast<bf16x8*>(&kS[r * 72 + c0 + 8]) = k1;
        *reinterpret_cast<bf16x8*>(&vS[r * 72 + c0])     = v0;
        *reinterpret_cast<bf16x8*>(&vS[r * 72 + c0 + 8]) = v1;
        bf16x8 s0 = sigma8(k0), s1 = sigma8(k1);
        *reinterpret_cast<bf16x8*>(skg + sb + (size_t)r * 64 + c0)     = s0;
        *reinterpret_cast<bf16x8*>(skg + sb + (size_t)r * 64 + c0 + 8) = s1;
#pragma unroll
        for (int j = 0; j < 8; j++) {
            skT[(c0 + j) * 72 + r]     = s0[j];
            skT[(c0 + 8 + j) * 72 + r] = s1[j];
            vT[(c0 + j) * 72 + r]      = v0[j];
            vT[(c0 + 8 + j) * 72 + r]  = v1[j];
        }
    }
    __syncthreads();

    if (tid < 64) {
        float acc = 0.f;
#pragma unroll 8
        for (int t = 0; t < 64; t++) acc += (float)skT[tid * 72 + t];
        csum[((size_t)bh * 64 + s) * 64 + tid] = acc;
    }
    *reinterpret_cast<bf16x8*>(skTg + sb + (size_t)r * 64 + c0) =
        *reinterpret_cast<const bf16x8*>(&skT[r * 72 + c0]);
    *reinterpret_cast<bf16x8*>(skTg + sb + (size_t)r * 64 + c0 + 8) =
        *reinterpret_cast<const bf16x8*>(&skT[r * 72 + c0 + 8]);
    *reinterpret_cast<bf16x8*>(vp + (size_t)r * QKV_STR + c0) =
        *reinterpret_cast<const bf16x8*>(&vT[r * 72 + c0]);
    *reinterpret_cast<bf16x8*>(vp + (size_t)r * QKV_STR + c0 + 8) =
        *reinterpret_cast<const bf16x8*>(&vT[r * 72 + c0 + 8]);

    {
        bf16x8 aq[2];
#pragma unroll
        for (int ks = 0; ks < 2; ks++)
            aq[ks] = *reinterpret_cast<const bf16x8*>(qp + (size_t)(w * 16 + lr) * QKV_STR + lk * 8 + ks * 32);
        f32x4 sc[4];
#pragma unroll
        for (int ct = 0; ct < 4; ct++) {
            sc[ct] = (f32x4){0.f, 0.f, 0.f, 0.f};
#pragma unroll
            for (int ks = 0; ks < 2; ks++) {
                bf16x8 bfrag = *reinterpret_cast<const bf16x8*>(&kS[(ct * 16 + lr) * 72 + lk * 8 + ks * 32]);
                sc[ct] = __builtin_amdgcn_mfma_f32_16x16x32_bf16(aq[ks], bfrag, sc[ct], 0, 0, 0);
            }
        }
#pragma unroll
        for (int ct = 0; ct < 4; ct++)
#pragma unroll
            for (int j = 0; j < 4; j++)
                scr[(w * 16 + lk * 4 + j) * 68 + ct * 16 + lr] = sc[ct][j] * 0.125f;
    }
    __syncthreads();

    {
        float p[16];
        float mx = -3.4e38f;
        const float* srow_p = &scr[r * 68 + c0];
#pragma unroll
        for (int i = 0; i < 16; i++) {
            int c = c0 + i;
            float v = (c <= r) ? srow_p[i] : -3.4e38f;
            p[i] = v;
            mx = fmaxf(mx, v);
        }
        mx = fmaxf(mx, __shfl_xor(mx, 1));
        mx = fmaxf(mx, __shfl_xor(mx, 2));
        float sum = 0.f;
#pragma unroll
        for (int i = 0; i < 16; i++) {
            int c = c0 + i;
            float e = (c <= r) ? __expf(p[i] - mx) : 0.f;
            p[i] = e;
            sum += e;
        }
        sum += __shfl_xor(sum, 1);
        sum += __shfl_xor(sum, 2);
        float inv = 1.f / sum;
        bf16x8 p0, p1;
#pragma unroll
        for (int j = 0; j < 8; j++) {
            p0[j] = (bf16_t)(p[j] * inv);
            p1[j] = (bf16_t)(p[8 + j] * inv);
        }
        *reinterpret_cast<bf16x8*>(&pS[r * 72 + c0])     = p0;
        *reinterpret_cast<bf16x8*>(&pS[r * 72 + c0 + 8]) = p1;
    }
    __syncthreads();

    {
        f32x4 ad[4];
#pragma unroll
        for (int ct = 0; ct < 4; ct++) {
            ad[ct] = (f32x4){0.f, 0.f, 0.f, 0.f};
#pragma unroll
            for (int ks = 0; ks < 2; ks++) {
                bf16x8 afrag = *reinterpret_cast<const bf16x8*>(&pS[(w * 16 + lr) * 72 + lk * 8 + ks * 32]);
                bf16x8 bfrag = *reinterpret_cast<const bf16x8*>(&vT[(ct * 16 + lr) * 72 + lk * 8 + ks * 32]);
                ad[ct] = __builtin_amdgcn_mfma_f32_16x16x32_bf16(afrag, bfrag, ad[ct], 0, 0, 0);
            }
        }
#pragma unroll
        for (int ct = 0; ct < 4; ct++)
#pragma unroll
            for (int j = 0; j < 4; j++)
                kS[(w * 16 + lk * 4 + j) * 72 + ct * 16 + lr] = (bf16_t)ad[ct][j];
    }
    __syncthreads();
    *reinterpret_cast<bf16x8*>(Adot + sb + (size_t)r * 64 + c0) =
        *reinterpret_cast<const bf16x8*>(&kS[r * 72 + c0]);
    *reinterpret_cast<bf16x8*>(Adot + sb + (size_t)r * 64 + c0 + 8) =
        *reinterpret_cast<const bf16x8*>(&kS[r * 72 + c0 + 8]);
}

// ---------------- z prefix over segments (batched loads, register prefix) ----------------
__global__ __launch_bounds__(64) void zprefix_kernel(const float* __restrict__ csum,
                                                     float* __restrict__ zx,
                                                     float* __restrict__ zfin) {
    int bh = blockIdx.x;
    int d = threadIdx.x;
    float c[64];
#pragma unroll
    for (int s = 0; s < 64; s++)
        c[s] = csum[((size_t)bh * 64 + s) * 64 + d];
    float z = 0.f;
#pragma unroll
    for (int s = 0; s < 64; s++) {
        zx[((size_t)bh * 64 + s) * 64 + d] = z;
        z += c[s];
    }
    zfin[bh * 64 + d] = z;
}

// ---------------- k-side denominators only: 1/(sigma(k) . z + eps) (dense sigma(k)) -------
__global__ __launch_bounds__(64) void denomk_kernel(const bf16_t* __restrict__ skg,
                                                    const float* __restrict__ zx,
                                                    float* __restrict__ invk) {
    __shared__ float zL[64];
    int u = blockIdx.x;
    int tid = threadIdx.x;
    zL[tid] = zx[(size_t)u * 64 + tid];
    __syncthreads();
    const bf16_t* src = skg + (size_t)u * 4096 + (size_t)tid * 64;
    float acc = 0.f;
#pragma unroll
    for (int blk = 0; blk < 8; blk++) {
        bf16x8 v = *reinterpret_cast<const bf16x8*>(src + blk * 8);
#pragma unroll
        for (int j = 0; j < 8; j++)
            acc = __builtin_fmaf((float)v[j], zL[blk * 8 + j], acc);
    }
    invk[(size_t)u * 64 + tid] = 1.f / (acc + 1e-6f);
}

// ---------------- k-side recurrence scan: 1 wave per block, no barriers, depth-1 prefetch ----
// grid 256: bh = blk & 63, cq = blk >> 6 (column quarter). M cols c0..c0+15 per block.
__global__ __launch_bounds__(64, 1) void scan_kernel(const bf16_t* __restrict__ QKV,
                                                     const bf16_t* __restrict__ skg,
                                                     const bf16_t* __restrict__ skTg,
                                                     const float* __restrict__ invk,
                                                     bf16_t* __restrict__ Msnap,
                                                     float* __restrict__ Mfin) {
    __shared__ bf16_t MbL[16 * 72];  // M^T slice (swizzled rows)
    __shared__ bf16_t uTL[16 * 72];  // v^T -> u^T slice (swizzled)
    __shared__ float  ikL[64];

    int blk = blockIdx.x;
    int bh = blk & 63, cq = blk >> 6;
    int c0 = cq << 4;
    int b = bh >> 4, h = bh & 15;
    int lane = threadIdx.x;
    int lr = lane & 15, lk = lane >> 4;
    int vr = lane >> 2, vt0 = (lane & 3) << 4;

    const bf16_t* vTb = QKV + 2048;
    size_t chbase = (size_t)(b * 4096) * QKV_STR + (size_t)h * 64;
    size_t stbase = (size_t)bh * 64 * 4096;
    const size_t SEG = (size_t)64 * QKV_STR;

    auto swz = [](bf16_t* base, int row, int intra) -> bf16_t* {
        return (bf16_t*)((char*)base + row * 144 + (intra ^ ((row & 7) << 4)));
    };

    for (int i = lane; i < 16 * 72; i += 64) MbL[i] = (bf16_t)0.f;
    f32x4 Mreg[4];
#pragma unroll
    for (int rt = 0; rt < 4; rt++) Mreg[rt] = (f32x4){0.f, 0.f, 0.f, 0.f};

    bf16x8 cK[4][2], cT[4][2];
#pragma unroll
    for (int rt = 0; rt < 4; rt++)
#pragma unroll
        for (int ks = 0; ks < 2; ks++) {
            cK[rt][ks] = *reinterpret_cast<const bf16x8*>(
                skg + stbase + (size_t)(rt * 16 + lr) * 64 + lk * 8 + ks * 32);
            cT[rt][ks] = *reinterpret_cast<const bf16x8*>(
                skTg + stbase + (size_t)(rt * 16 + lr) * 64 + lk * 8 + ks * 32);
        }
    {
        bf16x8 v0 = *reinterpret_cast<const bf16x8*>(vTb + chbase + (size_t)(c0 + vr) * QKV_STR + vt0);
        bf16x8 v1 = *reinterpret_cast<const bf16x8*>(vTb + chbase + (size_t)(c0 + vr) * QKV_STR + vt0 + 8);
        *reinterpret_cast<bf16x8*>(swz(uTL, vr, vt0 * 2))      = v0;
        *reinterpret_cast<bf16x8*>(swz(uTL, vr, vt0 * 2 + 16)) = v1;
        ikL[lane] = invk[(size_t)bh * 4096 + lane];
    }

    for (int s = 0; s < 64; s++) {
        bf16x8 nK[4][2], nT[4][2], nv0, nv1;
        float nik = 0.f;
        if (s < 63) {
            size_t vs2 = chbase + (size_t)(s + 1) * SEG;
            size_t sb2 = stbase + (size_t)(s + 1) * 4096;
#pragma unroll
            for (int rt = 0; rt < 4; rt++)
#pragma unroll
                for (int ks = 0; ks < 2; ks++) {
                    nK[rt][ks] = *reinterpret_cast<const bf16x8*>(
                        skg + sb2 + (size_t)(rt * 16 + lr) * 64 + lk * 8 + ks * 32);
                    nT[rt][ks] = *reinterpret_cast<const bf16x8*>(
                        skTg + sb2 + (size_t)(rt * 16 + lr) * 64 + lk * 8 + ks * 32);
                }
            nv0 = *reinterpret_cast<const bf16x8*>(vTb + vs2 + (size_t)(c0 + vr) * QKV_STR + vt0);
            nv1 = *reinterpret_cast<const bf16x8*>(vTb + vs2 + (size_t)(c0 + vr) * QKV_STR + vt0 + 8);
            nik = invk[(size_t)bh * 4096 + (size_t)(s + 1) * 64 + lane];
        }
        __builtin_amdgcn_sched_barrier(0);

        // MFMA1: Y = sigma(k) @ M[:, c0:c0+16]
        bf16x8 mb0 = *reinterpret_cast<const bf16x8*>(swz(MbL, lr, lk * 16));
        bf16x8 mb1 = *reinterpret_cast<const bf16x8*>(swz(MbL, lr, lk * 16 + 64));
        f32x4 Y[4];
#pragma unroll
        for (int rt = 0; rt < 4; rt++) {
            Y[rt] = (f32x4){0.f, 0.f, 0.f, 0.f};
            Y[rt] = __builtin_amdgcn_mfma_f32_16x16x32_bf16(cK[rt][0], mb0, Y[rt], 0, 0, 0);
            Y[rt] = __builtin_amdgcn_mfma_f32_16x16x32_bf16(cK[rt][1], mb1, Y[rt], 0, 0, 0);
        }

        // epilogue: u = v - Y*invk[t], in place in uTL
#pragma unroll
        for (int rt = 0; rt < 4; rt++) {
            bf16x4 vv = *reinterpret_cast<const bf16x4*>(swz(uTL, lr, rt * 32 + lk * 8));
            bf16x4 uu;
#pragma unroll
            for (int j = 0; j < 4; j++) {
                float ik = ikL[rt * 16 + lk * 4 + j];
                uu[j] = (bf16_t)((float)vv[j] - Y[rt][j] * ik);
            }
            *reinterpret_cast<bf16x4*>(swz(uTL, lr, rt * 32 + lk * 8)) = uu;
        }

        // MFMA2: M[:, c0:+16] += sigma(k)^T @ u
        bf16x8 ub0 = *reinterpret_cast<const bf16x8*>(swz(uTL, lr, lk * 16));
        bf16x8 ub1 = *reinterpret_cast<const bf16x8*>(swz(uTL, lr, lk * 16 + 64));
#pragma unroll
        for (int rt = 0; rt < 4; rt++) {
            Mreg[rt] = __builtin_amdgcn_mfma_f32_16x16x32_bf16(cT[rt][0], ub0, Mreg[rt], 0, 0, 0);
            Mreg[rt] = __builtin_amdgcn_mfma_f32_16x16x32_bf16(cT[rt][1], ub1, Mreg[rt], 0, 0, 0);
        }

        // refresh bf16 M^T slice + snapshot store (M_{s+1})
#pragma unroll
        for (int rt = 0; rt < 4; rt++) {
            bf16x4 mp;
#pragma unroll
            for (int j = 0; j < 4; j++) mp[j] = (bf16_t)Mreg[rt][j];
            *reinterpret_cast<bf16x4*>(swz(MbL, lr, rt * 32 + lk * 8)) = mp;
            if (s < 63)
                *reinterpret_cast<bf16x4*>(
                    Msnap + (((size_t)bh * 64 + s + 1) * 64 + c0 + lr) * 64 + rt * 16 + lk * 4) = mp;
        }

        if (s < 63) {
#pragma unroll
            for (int rt = 0; rt < 4; rt++)
#pragma unroll
                for (int ks = 0; ks < 2; ks++) { cK[rt][ks] = nK[rt][ks]; cT[rt][ks] = nT[rt][ks]; }
            *reinterpret_cast<bf16x8*>(swz(uTL, vr, vt0 * 2))      = nv0;
            *reinterpret_cast<bf16x8*>(swz(uTL, vr, vt0 * 2 + 16)) = nv1;
            ikL[lane] = nik;
        }
    }

    // final M slice (f32)
#pragma unroll
    for (int rt = 0; rt < 4; rt++)
#pragma unroll
        for (int j = 0; j < 4; j++)
            Mfin[(size_t)bh * 4096 + (size_t)(rt * 16 + lk * 4 + j) * 64 + c0 + lr] = Mreg[rt][j];
}

// ---------------- parallel combine: A_mem from snapshots, inline q-denominator, beta-blend ----
__global__ __launch_bounds__(256) void combine_kernel(const bf16_t* __restrict__ QKV,
                                                      const bf16_t* __restrict__ Msnap,
                                                      const bf16_t* __restrict__ Adot,
                                                      const float* __restrict__ zx,
                                                      const float* __restrict__ beta_param,
                                                      bf16_t* __restrict__ Op) {
    __shared__ bf16_t oS[64 * 72];
    __shared__ bf16_t adS[64 * 72];
    __shared__ float  iq[64];
    __shared__ float  zL[64];

    int u = blockIdx.x;
    int bh = u >> 6, s = u & 63;
    int b = bh >> 4, h = bh & 15;
    int tid = threadIdx.x;
    int w = tid >> 6, lane = tid & 63;
    int lr = lane & 15, lk = lane >> 4;
    int r = tid >> 2, c0 = (tid & 3) << 4;

    const bf16_t* qp = QKV + (size_t)(b * 4096 + s * 64) * QKV_STR + (size_t)h * 64;
    size_t vsegO = ((size_t)b * 4096 + s * 64) * 1024 + (size_t)h * 64;
    size_t sb = ((size_t)bh * 64 + s) * 4096;
    size_t ib = ((size_t)bh * 64 + s) * 64;

    float beta = 1.f / (1.f + __expf(-beta_param[h]));
    float omb = 1.f - beta;

    *reinterpret_cast<bf16x8*>(&adS[r * 72 + c0]) =
        *reinterpret_cast<const bf16x8*>(Adot + sb + (size_t)r * 64 + c0);
    *reinterpret_cast<bf16x8*>(&adS[r * 72 + c0 + 8]) =
        *reinterpret_cast<const bf16x8*>(Adot + sb + (size_t)r * 64 + c0 + 8);
    if (tid < 64) {
        zL[tid] = zx[ib + tid];
        iq[tid] = 0.f;
    }
    __syncthreads();

    f32x4 Y[4];
#pragma unroll
    for (int ct = 0; ct < 4; ct++) Y[ct] = (f32x4){0.f, 0.f, 0.f, 0.f};
    if (s > 0) {
        bf16x8 aq[2];
#pragma unroll
        for (int ks = 0; ks < 2; ks++)
            aq[ks] = sigma8(*reinterpret_cast<const bf16x8*>(
                qp + (size_t)(w * 16 + lr) * QKV_STR + lk * 8 + ks * 32));
        float dq = 0.f;
#pragma unroll
        for (int ks = 0; ks < 2; ks++)
#pragma unroll
            for (int j = 0; j < 8; j++)
                dq = __builtin_fmaf((float)aq[ks][j], zL[ks * 32 + lk * 8 + j], dq);
        dq += __shfl_xor(dq, 16);
        dq += __shfl_xor(dq, 32);
        if (lk == 0) iq[w * 16 + lr] = 1.f / (dq + 1e-6f);
#pragma unroll
        for (int ct = 0; ct < 4; ct++)
#pragma unroll
            for (int ks = 0; ks < 2; ks++) {
                bf16x8 bfrag = *reinterpret_cast<const bf16x8*>(
                    Msnap + sb + (size_t)(ct * 16 + lr) * 64 + lk * 8 + ks * 32);
                Y[ct] = __builtin_amdgcn_mfma_f32_16x16x32_bf16(aq[ks], bfrag, Y[ct], 0, 0, 0);
            }
    }
    __syncthreads();

#pragma unroll
    for (int ct = 0; ct < 4; ct++) {
        int colc = ct * 16 + lr;
#pragma unroll
        for (int j = 0; j < 4; j++) {
            int t = w * 16 + lk * 4 + j;
            float o = beta * (Y[ct][j] * iq[t]) + omb * (float)adS[t * 72 + colc];
            oS[t * 72 + colc] = (bf16_t)o;
        }
    }
    __syncthreads();

    *reinterpret_cast<bf16x8*>(Op + vsegO + (size_t)r * 1024 + c0) =
        *reinterpret_cast<const bf16x8*>(&oS[r * 72 + c0]);
    *reinterpret_cast<bf16x8*>(Op + vsegO + (size_t)r * 1024 + c0 + 8) =
        *reinterpret_cast<const bf16x8*>(&oS[r * 72 + c0 + 8]);
}

// ---------------- final means over batch ----------------
__global__ __launch_bounds__(256) void mean_kernel(const float* __restrict__ Mfin,
                                                   const float* __restrict__ zfin,
                                                   float* __restrict__ out) {
    int idx = blockIdx.x * 256 + threadIdx.x;
    if (idx < 65536) {
        out[16777216 + idx] = 0.25f * (Mfin[idx] + Mfin[idx + 65536] +
                                       Mfin[idx + 131072] + Mfin[idx + 196608]);
    } else if (idx < 66560) {
        int j = idx - 65536;
        out[16842752 + j] = 0.25f * (zfin[j] + zfin[j + 1024] + zfin[j + 2048] + zfin[j + 3072]);
    }
}

extern "C" void kernel_launch(void* const* d_in, const int* in_sizes, int n_in,
                              void* d_out, int out_size, void* d_ws, size_t ws_size,
                              hipStream_t stream) {
    const float* x      = (const float*)d_in[0];
    const float* Wq     = (const float*)d_in[1];
    const float* Wk     = (const float*)d_in[2];
    const float* Wv     = (const float*)d_in[3];
    const float* Wo     = (const float*)d_in[4];
    const float* beta_p = (const float*)d_in[5];
    float* out = (float*)d_out;
    char* ws = (char*)d_ws;

    bf16_t* xb   = (bf16_t*)ws;                         // [0, 33.5MB)
    bf16_t* Adot = xb;                                  // alias (xb dead after QKV GEMM)
    bf16_t* Wqb  = (bf16_t*)(ws + 33554432);            // Wq,Wk,Wv contiguous = [3072][1024]
    bf16_t* Wkb  = (bf16_t*)(ws + 35651584);
    bf16_t* Wvb  = (bf16_t*)(ws + 37748736);
    bf16_t* Wob  = (bf16_t*)(ws + 39845888);
    bf16_t* QKV  = (bf16_t*)(ws + 41943040);            // [16384][3072] bf16
    bf16_t* skT  = (bf16_t*)(ws + 142606336);
    bf16_t* Op   = (bf16_t*)(ws + 176160768);
    float*  csum = (float*)(ws + 209715200);
    float*  zx   = (float*)(ws + 210763776);
    float*  invk = (float*)(ws + 212860928);
    float*  Mfin = (float*)(ws + 213909504);
    float*  zfin = (float*)(ws + 214958080);
    bf16_t* Msnap = (bf16_t*)d_out;                     // d_out bf16 [0, 16.7M)  (dead until O-GEMM)
    bf16_t* skg   = (bf16_t*)d_out + 16777216;          // d_out bf16 [16.7M, 33.5M): dense sigma(k)

    // all casts in one dispatch (x + 4 weights)
    cast_all_kernel<<<dim3(20480), dim3(256), 0, stream>>>(x, Wq, Wk, Wv, Wo,
                                                           xb, Wqb, Wkb, Wvb, Wob);

    // fused QKV projection: [16384,1024] x [3072,1024]^T -> [16384,3072]
    gemm256<1><<<dim3(768), dim3(512), 0, stream>>>(xb, Wqb, (void*)QKV, 16384, 3072, 1024);

    attn_kernel<<<dim3(4096), dim3(256), 0, stream>>>(QKV, skT, skg, csum, Adot);
    zprefix_kernel<<<dim3(64), dim3(64), 0, stream>>>(csum, zx, zfin);
    denomk_kernel<<<dim3(4096), dim3(64), 0, stream>>>(skg, zx, invk);
    scan_kernel<<<dim3(256), dim3(64), 0, stream>>>(QKV, skg, skT, invk, Msnap, Mfin);
    combine_kernel<<<dim3(4096), dim3(256), 0, stream>>>(QKV, Msnap, Adot, zx, beta_p, Op);

    gemm256<0><<<dim3(256), dim3(512), 0, stream>>>(Op, Wob, d_out, 16384, 1024, 1024);
    mean_kernel<<<dim3(260), dim3(256), 0, stream>>>(Mfin, zfin, out);
}